// Round 8
// baseline (228.824 us; speedup 1.0000x reference)
//
#include <hip/hip_runtime.h>
#include <math.h>

typedef __attribute__((ext_vector_type(8))) short short8;
typedef __attribute__((ext_vector_type(4))) float floatx4;

__device__ __forceinline__ unsigned short bf16r(float f) {
  union { float f; unsigned int u; } v; v.f = f;
  unsigned int u = v.u;
  return (unsigned short)((u + 0x7fffu + ((u >> 16) & 1u)) >> 16);
}
// round-half-up pack (sampling path; 2 ops)
__device__ __forceinline__ unsigned int bf16h(float f) {
  union { float f; unsigned int u; } v; v.f = f;
  return (v.u + 0x8000u) >> 16;
}
__device__ __forceinline__ float bf2f(unsigned int u) {
  union { unsigned int u; float f; } v; v.u = u << 16; return v.f;
}
// async global->LDS DMA, 16B/lane; LDS dst = wave-uniform base + lane*16
__device__ __forceinline__ void glds16(const void* g, void* l) {
  __builtin_amdgcn_global_load_lds(
      (const __attribute__((address_space(1))) unsigned int*)g,
      (__attribute__((address_space(3))) unsigned int*)l, 16, 0, 0);
}

// ---------------------------------------------------------------------------
// K0: weight prep (bf16, MFMA-frag layouts) + fused tables
// ---------------------------------------------------------------------------
__global__ __launch_bounds__(256) void k_prep(
    const float* __restrict__ w_dcn, const float* __restrict__ w_off,
    const float* __restrict__ b_dcn,
    const float* __restrict__ bn_g, const float* __restrict__ bn_b,
    const float* __restrict__ bn_m, const float* __restrict__ bn_v,
    const float* __restrict__ w_up, const float* __restrict__ w1x1,
    unsigned short* __restrict__ wt_dcn, unsigned short* __restrict__ wt_off,
    float* __restrict__ vtab, float* __restrict__ bntab) {
  int e = blockIdx.x * 256 + threadIdx.x;
  if (e < 294912) {
    int cc = e & 31, o = (e >> 5) & 127, s = e >> 12;
    int k = s % 9, cg = s / 9, c = cg * 32 + cc;
    wt_dcn[e] = bf16r(w_dcn[(o * 256 + c) * 9 + k]);
  }
  if (e < 73728) {
    int cc = e & 31, oc = (e >> 5) & 31, s = e >> 10;
    int k = s % 9, cg = s / 9, c = cg * 32 + cc;
    wt_off[e] = (oc < 27) ? bf16r(w_off[(oc * 256 + c) * 9 + k]) : (unsigned short)0;
  }
  if (e < 2048) {
    int o = e >> 4;
    vtab[e] = w1x1[o] * w_up[e];
  }
  if (e < 128) {
    float g = bn_g[e] * rsqrtf(bn_v[e] + 1e-5f);
    bntab[e] = g;
    bntab[128 + e] = (b_dcn[e] - bn_m[e]) * g + bn_b[e];
  }
}

// ---------------------------------------------------------------------------
// K0b: x (fp32 NCHW) -> xT (bf16, [b][pixel][c]); float4 loads (4px/thread)
// ---------------------------------------------------------------------------
__global__ __launch_bounds__(256) void k_xt(
    const float* __restrict__ x, unsigned short* __restrict__ xT) {
  __shared__ unsigned short sx[32 * 264];
  int b = blockIdx.x >> 7, px0 = (blockIdx.x & 127) * 32;
  int t = threadIdx.x;
  int pg = (t & 7) * 4, cg = t >> 3;   // 8 px-quads x 32 c-groups of 8
  const float* xsrc = x + (((size_t)(b * 256 + cg * 8)) << 12) + px0 + pg;
#pragma unroll
  for (int cc = 0; cc < 8; ++cc) {
    float4 v = *(const float4*)&xsrc[(size_t)cc << 12];
    int c = cg * 8 + cc;
    sx[(pg + 0) * 264 + c] = bf16r(v.x);
    sx[(pg + 1) * 264 + c] = bf16r(v.y);
    sx[(pg + 2) * 264 + c] = bf16r(v.z);
    sx[(pg + 3) * 264 + c] = bf16r(v.w);
  }
  __syncthreads();
#pragma unroll
  for (int j = 0; j < 4; ++j) {
    int unit = t + j * 256;
    int p = unit >> 5, chunk = unit & 31;
    uint4 v = *(const uint4*)&sx[p * 264 + chunk * 8];
    *(uint4*)&xT[((size_t)((b << 12) + px0 + p)) * 256 + chunk * 8] = v;
  }
}

// ---------------------------------------------------------------------------
// K1: offset conv via MFMA, zero LDS / zero barriers, batched loads (MLP).
// ---------------------------------------------------------------------------
__global__ __launch_bounds__(256, 2) void k_offconv(
    const unsigned short* __restrict__ xT, const unsigned short* __restrict__ wt_off,
    const float* __restrict__ b_off, unsigned short* __restrict__ om) {
  int b = blockIdx.x >> 6, row = blockIdx.x & 63;
  int t = threadIdx.x, lane = t & 63, wvx = t >> 6;
  int l15 = lane & 15, quad = lane >> 4;
  int xcol = wvx * 16 + l15;
  const unsigned short* xb = xT + (((size_t)b) << 12) * 256;
  const short8 zz = {0, 0, 0, 0, 0, 0, 0, 0};

  int pixk[9]; bool vk[9];
#pragma unroll
  for (int k = 0; k < 9; ++k) {
    int yy = row + k / 3 - 1, xx = xcol + k % 3 - 1;
    vk[k] = ((unsigned)yy < 64u) & ((unsigned)xx < 64u);
    pixk[k] = vk[k] ? (yy * 64 + xx) : 0;
  }

  floatx4 acc[2];
  acc[0] = (floatx4){0.f, 0.f, 0.f, 0.f};
  acc[1] = (floatx4){0.f, 0.f, 0.f, 0.f};

  for (int cg = 0; cg < 8; ++cg) {
    int cb = cg * 32 + quad * 8;
    short8 bx[9];
#pragma unroll
    for (int k = 0; k < 9; ++k) {
      short8 v = *(const short8*)&xb[(size_t)pixk[k] * 256 + cb];
      bx[k] = vk[k] ? v : zz;
    }
#pragma unroll
    for (int k = 0; k < 9; ++k) {
      const unsigned short* wp = wt_off + (size_t)(cg * 9 + k) * 1024;
      short8 a0 = *(const short8*)&wp[l15 * 32 + quad * 8];
      short8 a1 = *(const short8*)&wp[(16 + l15) * 32 + quad * 8];
      acc[0] = __builtin_amdgcn_mfma_f32_16x16x32_bf16(a0, bx[k], acc[0], 0, 0, 0);
      acc[1] = __builtin_amdgcn_mfma_f32_16x16x32_bf16(a1, bx[k], acc[1], 0, 0, 0);
    }
  }
#pragma unroll
  for (int ot = 0; ot < 2; ++ot)
#pragma unroll
    for (int r = 0; r < 4; ++r) {
      int o = ot * 16 + quad * 4 + r;
      if (o < 27)
        om[(((size_t)(b * 27 + o)) << 12) + row * 64 + xcol] = bf16r(acc[ot][r] + b_off[o]);
    }
}

// ---------------------------------------------------------------------------
// K2: DCNv2 via MFMA + fused BN/ReLU + fused (upsample x 1x1) -> R.
// Ping-pong tap regs + double-buffered W; ALL next-phase vmem issued at
// phase START so the end-of-phase barrier drain has full latency cover.
// ---------------------------------------------------------------------------
__global__ __launch_bounds__(256, 2) void k_dcn(
    const unsigned short* __restrict__ xT, const unsigned short* __restrict__ wt,
    const unsigned short* __restrict__ om, const float* __restrict__ vtab,
    const float* __restrict__ bntab, float* __restrict__ R) {
  int b = blockIdx.x >> 6, row = blockIdx.x & 63;
  __shared__ unsigned short sW[2 * 12288];   // 2 x 24576 B
  __shared__ ushort4 s_ti[576];
  __shared__ float4 s_tw[576];
  int t = threadIdx.x, lane = t & 63, wvx = t >> 6;
  int l15 = lane & 15, quad = lane >> 4;

  for (int i = t; i < 576; i += 256) {
    int k = i >> 6, p = i & 63;
    float o1 = bf2f(om[(((size_t)(b * 27 + k)) << 12) + row * 64 + p]);
    float o2 = bf2f(om[(((size_t)(b * 27 + 9 + k)) << 12) + row * 64 + p]);
    float mv = bf2f(om[(((size_t)(b * 27 + 18 + k)) << 12) + row * 64 + p]);
    float m = 1.f / (1.f + __expf(-mv));
    float py = (float)(row + k / 3 - 1) + o1;
    float pxf = (float)(p + (k % 3) - 1) + o2;
    float fy = floorf(py), fx = floorf(pxf);
    int iy = (int)fy, ix = (int)fx;
    float wy1 = py - fy, wy0 = 1.f - wy1;
    float wx1 = pxf - fx, wx0 = 1.f - wx1;
    bool y0ok = (iy >= 0) & (iy < 64), y1ok = (iy >= -1) & (iy < 63);
    bool x0ok = (ix >= 0) & (ix < 64), x1ok = (ix >= -1) & (ix < 63);
    int iy0 = min(max(iy, 0), 63), iy1 = min(max(iy + 1, 0), 63);
    int ix0 = min(max(ix, 0), 63), ix1 = min(max(ix + 1, 0), 63);
    s_ti[i] = make_ushort4((unsigned short)(iy0 * 64 + ix0), (unsigned short)(iy0 * 64 + ix1),
                           (unsigned short)(iy1 * 64 + ix0), (unsigned short)(iy1 * 64 + ix1));
    float4 w;
    w.x = (y0ok && x0ok) ? m * wy0 * wx0 : 0.f;
    w.y = (y0ok && x1ok) ? m * wy0 * wx1 : 0.f;
    w.z = (y1ok && x0ok) ? m * wy1 * wx0 : 0.f;
    w.w = (y1ok && x1ok) ? m * wy1 * wx1 : 0.f;
    s_tw[i] = w;
  }
  __syncthreads();   // s_ti/s_tw ready (read-only hereafter)

  int px = wvx * 16 + l15;
  const unsigned short* xb = xT + (((size_t)b) << 12) * 256;

  floatx4 acc[8];
#pragma unroll
  for (int i = 0; i < 8; ++i) acc[i] = (floatx4){0.f, 0.f, 0.f, 0.f};

  uint4 trawA[12], trawB[12];

#define ISSUE_TAPS(PH, DST) { \
    int cb_ = ((PH) / 3) * 32 + quad * 8; \
    _Pragma("unroll") \
    for (int kk_ = 0; kk_ < 3; ++kk_) { \
      int k_ = ((PH) % 3) * 3 + kk_; \
      ushort4 ti_ = s_ti[(k_ << 6) + px]; \
      DST[kk_ * 4 + 0] = *(const uint4*)&xb[(size_t)ti_.x * 256 + cb_]; \
      DST[kk_ * 4 + 1] = *(const uint4*)&xb[(size_t)ti_.y * 256 + cb_]; \
      DST[kk_ * 4 + 2] = *(const uint4*)&xb[(size_t)ti_.z * 256 + cb_]; \
      DST[kk_ * 4 + 3] = *(const uint4*)&xb[(size_t)ti_.w * 256 + cb_]; \
    } }

#define GLDS_W(PH) { \
    const unsigned short* ws_ = wt + (size_t)(PH) * 12288; \
    unsigned short* dst_ = sW + ((PH) & 1) * 12288; \
    _Pragma("unroll") \
    for (int i_ = 0; i_ < 6; ++i_) { \
      int blk_ = wvx * 6 + i_; \
      glds16(ws_ + (size_t)blk_ * 512 + lane * 8, dst_ + blk_ * 512); \
    } }

#define PHASE(PH, CUR, NXT) { \
    if ((PH) < 23) { GLDS_W((PH) + 1); ISSUE_TAPS((PH) + 1, NXT); } \
    const unsigned short* buf_ = sW + ((PH) & 1) * 12288; \
    _Pragma("unroll") \
    for (int kk = 0; kk < 3; ++kk) { \
      int k_ = ((PH) % 3) * 3 + kk; \
      float4 tw = s_tw[(k_ << 6) + px]; \
      union { uint4 u; short8 s; } x0, x1, x2, x3; \
      x0.u = CUR[kk * 4 + 0]; x1.u = CUR[kk * 4 + 1]; \
      x2.u = CUR[kk * 4 + 2]; x3.u = CUR[kk * 4 + 3]; \
      float r[8]; \
      _Pragma("unroll") \
      for (int j = 0; j < 8; ++j) \
        r[j] = tw.x * bf2f((unsigned short)x0.s[j]) + tw.y * bf2f((unsigned short)x1.s[j]) + \
               tw.z * bf2f((unsigned short)x2.s[j]) + tw.w * bf2f((unsigned short)x3.s[j]); \
      union { uint4 u; short8 s; } bu; \
      bu.u = make_uint4(bf16h(r[0]) | (bf16h(r[1]) << 16), bf16h(r[2]) | (bf16h(r[3]) << 16), \
                        bf16h(r[4]) | (bf16h(r[5]) << 16), bf16h(r[6]) | (bf16h(r[7]) << 16)); \
      _Pragma("unroll") \
      for (int ot = 0; ot < 8; ++ot) { \
        short8 af = *(const short8*)&buf_[(kk * 128 + ot * 16 + l15) * 32 + quad * 8]; \
        acc[ot] = __builtin_amdgcn_mfma_f32_16x16x32_bf16(af, bu.s, acc[ot], 0, 0, 0); \
      } \
    } \
    __syncthreads(); }

  ISSUE_TAPS(0, trawA);
  GLDS_W(0);
  __syncthreads();   // phase-0 W complete + taps in flight->regs

  for (int p2 = 0; p2 < 12; ++p2) {
    PHASE(p2 * 2, trawA, trawB);
    PHASE(p2 * 2 + 1, trawB, trawA);
  }

  // epilogue: BN+ReLU then R_t[px] = sum_o v[o][t]*yv, reduced over quads
  float* sv = (float*)sW;          // 2048 vtab + 256 bn (9216 B <= 49152)
  float* sbn = sv + 2048;
  for (int i = t; i < 2048; i += 256) sv[i] = vtab[i];
  if (t < 256) sbn[t] = bntab[t];
  __syncthreads();

  float rpart[16];
#pragma unroll
  for (int i = 0; i < 16; ++i) rpart[i] = 0.f;
#pragma unroll
  for (int ot = 0; ot < 8; ++ot)
#pragma unroll
    for (int r = 0; r < 4; ++r) {
      int o = ot * 16 + quad * 4 + r;
      float yv = fmaxf(acc[ot][r] * sbn[o] + sbn[128 + o], 0.f);
      const float* vp = &sv[o * 16];
#pragma unroll
      for (int tt = 0; tt < 16; ++tt) rpart[tt] += vp[tt] * yv;
    }
#pragma unroll
  for (int tt = 0; tt < 16; ++tt) {
    rpart[tt] += __shfl_xor(rpart[tt], 16, 64);
    rpart[tt] += __shfl_xor(rpart[tt], 32, 64);
  }
  size_t rbase = ((size_t)((b << 12) + row * 64 + px)) * 16;
#pragma unroll
  for (int j = 0; j < 4; ++j) R[rbase + quad * 4 + j] = rpart[quad * 4 + j];
}

// ---------------------------------------------------------------------------
// K3: upsample+1x1+sigmoid from R maps, LDS-tiled (coalesced R reads).
// block = 16x16 out tile; grid = 8b x 8 x 8.
// ---------------------------------------------------------------------------
__global__ __launch_bounds__(256) void k_upb(
    const float* __restrict__ R, float* __restrict__ out) {
  __shared__ float sR[10 * 10 * 16];   // 6.4 KB
  int b = blockIdx.x >> 6;
  int ty = (blockIdx.x >> 3) & 7, tx = blockIdx.x & 7;
  int Y0 = ty * 16, X0 = tx * 16;
  int ib = (Y0 >> 1) - 1, jb = (X0 >> 1) - 1;
  int t = threadIdx.x;
  const float* Rb = R + (((size_t)b) << 12) * 16;
  for (int idx = t; idx < 1600; idx += 256) {
    int ii = idx / 160, rem = idx - ii * 160;
    int jj = rem >> 4, tt = rem & 15;
    int gi = ib + ii, gj = jb + jj;
    float v = 0.f;
    if (((unsigned)gi < 64u) && ((unsigned)gj < 64u))
      v = Rb[(size_t)(gi * 64 + gj) * 16 + tt];
    sR[idx] = v;
  }
  __syncthreads();
  int X = X0 + (t & 15), Y = Y0 + (t >> 4);
  int li0, wu0, wu1, lj0, wv0, wv1;
  if (Y & 1) { li0 = ((Y - 1) >> 1) - ib; wu0 = 2; wu1 = 0; }
  else       { li0 = (Y / 2 - 1) - ib;    wu0 = 3; wu1 = 1; }
  if (X & 1) { lj0 = ((X - 1) >> 1) - jb; wv0 = 2; wv1 = 0; }
  else       { lj0 = (X / 2 - 1) - jb;    wv0 = 3; wv1 = 1; }
  int li1 = li0 + 1, lj1 = lj0 + 1;
  float s = sR[(li0 * 10 + lj0) * 16 + wu0 * 4 + wv0] +
            sR[(li0 * 10 + lj1) * 16 + wu0 * 4 + wv1] +
            sR[(li1 * 10 + lj0) * 16 + wu1 * 4 + wv0] +
            sR[(li1 * 10 + lj1) * 16 + wu1 * 4 + wv1];
  out[((size_t)b * 128 + Y) * 128 + X] = 1.f / (1.f + __expf(-s));
}

// ---------------------------------------------------------------------------
extern "C" void kernel_launch(void* const* d_in, const int* in_sizes, int n_in,
                              void* d_out, int out_size, void* d_ws, size_t ws_size,
                              hipStream_t stream) {
  const float* x        = (const float*)d_in[0];
  const float* w_dcn    = (const float*)d_in[1];
  const float* b_dcn    = (const float*)d_in[2];
  const float* w_off    = (const float*)d_in[3];
  const float* b_off    = (const float*)d_in[4];
  const float* bn_gamma = (const float*)d_in[5];
  const float* bn_beta  = (const float*)d_in[6];
  const float* bn_mean  = (const float*)d_in[7];
  const float* bn_var   = (const float*)d_in[8];
  const float* w_up     = (const float*)d_in[9];
  const float* w_1x1    = (const float*)d_in[10];
  float* out = (float*)d_out;

  // ws layout in FLOAT units (21.39 MB total):
  float* ws = (float*)d_ws;
  unsigned short* xT     = (unsigned short*)ws;                    // 8388608 ush
  unsigned short* wt_dcn = (unsigned short*)(ws + 4194304);        //  294912 ush
  unsigned short* wt_off = (unsigned short*)(ws + 4341760);        //   73728 ush
  float* vtab            = ws + 4378624;                           //    2048 f
  float* bntab           = ws + 4380672;                           //     256 f
  unsigned short* om     = (unsigned short*)(ws + 4380928);        //  884736 ush
  float* R               = ws + 4823296;                           //  524288 f

  k_prep<<<1152, 256, 0, stream>>>(w_dcn, w_off, b_dcn, bn_gamma, bn_beta,
                                   bn_mean, bn_var, w_up, w_1x1,
                                   wt_dcn, wt_off, vtab, bntab);
  k_xt<<<1024, 256, 0, stream>>>(x, xT);
  k_offconv<<<512, 256, 0, stream>>>(xT, wt_off, b_off, om);
  k_dcn<<<512, 256, 0, stream>>>(xT, wt_dcn, om, vtab, bntab, R);
  k_upb<<<512, 256, 0, stream>>>(R, out);
}